// Round 3
// baseline (261.766 us; speedup 1.0000x reference)
//
#include <hip/hip_runtime.h>

typedef short short8 __attribute__((ext_vector_type(8)));
typedef float f32x4 __attribute__((ext_vector_type(4)));

// ---------------- bf16 helpers ----------------

__device__ inline unsigned short f2bf(float f) {
    union { float f; unsigned u; } v; v.f = f;
    unsigned r = v.u + 0x7fffu + ((v.u >> 16) & 1u);
    return (unsigned short)(r >> 16);
}
__device__ inline unsigned pack2(float a, float b) {
    return (unsigned)f2bf(a) | ((unsigned)f2bf(b) << 16);
}
__device__ inline float bflo(unsigned u) { union { unsigned q; float f; } c; c.q = u << 16; return c.f; }
__device__ inline float bfhi(unsigned u) { union { unsigned q; float f; } c; c.q = u & 0xffff0000u; return c.f; }

#define ACC8(vv)                                     \
    acc[0] += bflo(vv.x); acc[1] += bfhi(vv.x);      \
    acc[2] += bflo(vv.y); acc[3] += bfhi(vv.y);      \
    acc[4] += bflo(vv.z); acc[5] += bfhi(vv.z);      \
    acc[6] += bflo(vv.w); acc[7] += bfhi(vv.w);

// Gather-accumulate over edges [beg,end); geti(k) supplies the row index.
// 16-wide batches; remainder via ONE masked 16-wide batch (indices clamped).
template <int TPN, typename F>
__device__ __forceinline__ void gather_acc(float acc[8], const uint4* __restrict__ x,
                                           int lane, int beg, int end, F geti) {
    int k = beg;
    for (; k + 16 <= end; k += 16) {
        int idx[16];
#pragma unroll
        for (int j = 0; j < 16; j++) idx[j] = geti(k + j);
        uint4 v[16];
#pragma unroll
        for (int j = 0; j < 16; j++) v[j] = x[(size_t)idx[j] * TPN + lane];
#pragma unroll
        for (int j = 0; j < 16; j++) { ACC8(v[j]) }
    }
    int r = end - k;
    if (r > 0) {
        int lim = end - 1;
        int idx[16];
#pragma unroll
        for (int j = 0; j < 16; j++) idx[j] = geti(min(k + j, lim));
        uint4 v[16];
#pragma unroll
        for (int j = 0; j < 16; j++) v[j] = x[(size_t)idx[j] * TPN + lane];
#pragma unroll
        for (int j = 0; j < 16; j++) {
            if (k + j < end) { ACC8(v[j]) }
        }
    }
}

// ---------------- CSR build: atomic-free two-level bucket sort ----------------

#define EPB 2048
#define NE 8
#define BSH 9
#define MAXBKT 128
#define DCAP 10240

__global__ __launch_bounds__(256) void mega1(const int* __restrict__ dst, int* __restrict__ cnt2d,
                                             int e, int nbkt, int nblk,
                                             const float4* __restrict__ feat, uint2* __restrict__ featb,
                                             int cvtb, int nf4,
                                             const float* __restrict__ W1, const float* __restrict__ Wh,
                                             const float* __restrict__ Wo,
                                             unsigned short* __restrict__ W1t, unsigned short* __restrict__ Wht,
                                             unsigned short* __restrict__ Wot) {
    __shared__ int hist[MAXBKT];
    int t = threadIdx.x, b = blockIdx.x;
    if (b < nblk) {
        for (int j = t; j < nbkt; j += 256) hist[j] = 0;
        __syncthreads();
        int base = b * EPB;
#pragma unroll
        for (int j = 0; j < NE; j++) {
            int idx = base + t + 256 * j;
            if (idx < e) atomicAdd(&hist[dst[idx] >> BSH], 1);
        }
        __syncthreads();
        for (int j = t; j < nbkt; j += 256) cnt2d[j * nblk + b] = hist[j];
    } else if (b < nblk + cvtb) {
        int i = (b - nblk) * 256 + t;
        if (i < nf4) {
            float4 v = feat[i];
            featb[i] = make_uint2(pack2(v.x, v.y), pack2(v.z, v.w));
        }
    } else {
        int i = (b - nblk - cvtb) * 256 + t;
        if (i < 16384) {
            int k = i >> 7, nn = i & 127;
            W1t[nn * 128 + k] = f2bf(W1[i]);
        } else if (i < 32768) {
            int j = i - 16384, k = j >> 7, nn = j & 127;
            Wht[nn * 128 + k] = f2bf(Wh[j]);
        } else if (i < 40960) {
            int j = i - 32768, k = j >> 6, nn = j & 63;
            Wot[nn * 128 + k] = f2bf(Wo[j]);
        }
    }
}

__global__ __launch_bounds__(512) void scanB1(int* __restrict__ cnt2d, int* __restrict__ totals, int nblk) {
    __shared__ int s[512];
    int t = threadIdx.x, b = blockIdx.x;
    int v = (t < nblk) ? cnt2d[b * nblk + t] : 0;
    s[t] = v;
    __syncthreads();
    for (int off = 1; off < 512; off <<= 1) {
        int u = (t >= off) ? s[t - off] : 0;
        __syncthreads();
        s[t] += u;
        __syncthreads();
    }
    if (t < nblk) cnt2d[b * nblk + t] = s[t] - v;
    if (t == nblk - 1) totals[b] = s[t];
}

__global__ __launch_bounds__(128) void scanB2(const int* __restrict__ totals, int* __restrict__ bbase,
                                              int* __restrict__ row_ptr, int nbkt, int n, int e) {
    __shared__ int s[128];
    int t = threadIdx.x;
    int v = (t < nbkt) ? totals[t] : 0;
    s[t] = v;
    __syncthreads();
    for (int off = 1; off < 128; off <<= 1) {
        int u = (t >= off) ? s[t - off] : 0;
        __syncthreads();
        s[t] += u;
        __syncthreads();
    }
    if (t < nbkt) bbase[t] = s[t] - v;
    if (t == 0) row_ptr[n] = e;
}

__global__ __launch_bounds__(256) void binC(const int* __restrict__ src, const int* __restrict__ dst,
                                            const int* __restrict__ cnt2d, const int* __restrict__ bbase,
                                            unsigned* __restrict__ pairs, int e, int nbkt, int nblk) {
    __shared__ int hist[MAXBKT], loff[MAXBKT], cur[MAXBKT], gb[MAXBKT];
    __shared__ int sc[256];
    __shared__ unsigned sorted[EPB];
    int t = threadIdx.x, blk = blockIdx.x;
    for (int b = t; b < nbkt; b += 256) hist[b] = 0;
    __syncthreads();
    int base = blk * EPB;
    int cnt = min(EPB, e - base);
    unsigned packed[NE];
    int bb[NE];
#pragma unroll
    for (int j = 0; j < NE; j++) {
        int idx = base + t + 256 * j;
        bb[j] = -1;
        if (idx < e) {
            unsigned s0 = (unsigned)src[idx], d = (unsigned)dst[idx];
            int b = (int)(d >> BSH);
            bb[j] = b;
            packed[j] = s0 | ((d & ((1u << BSH) - 1)) << 16) | ((unsigned)b << 25);
            atomicAdd(&hist[b], 1);
        }
    }
    __syncthreads();
    int v = (t < nbkt) ? hist[t] : 0;
    sc[t] = v;
    __syncthreads();
    for (int off = 1; off < 256; off <<= 1) {
        int u = (t >= off) ? sc[t - off] : 0;
        __syncthreads();
        sc[t] += u;
        __syncthreads();
    }
    if (t < nbkt) {
        int ex = sc[t] - v;
        loff[t] = ex;
        cur[t] = ex;
        gb[t] = bbase[t] + cnt2d[t * nblk + blk];
    }
    __syncthreads();
#pragma unroll
    for (int j = 0; j < NE; j++) {
        if (bb[j] >= 0) {
            int r = atomicAdd(&cur[bb[j]], 1);  // LDS only
            sorted[r] = packed[j];
        }
    }
    __syncthreads();
    for (int i = t; i < cnt; i += 256) {
        unsigned w = sorted[i];
        int b = (int)(w >> 25);
        pairs[gb[b] + (i - loff[b])] = w;
    }
}

__global__ __launch_bounds__(512) void buildD(const unsigned* __restrict__ pairs,
                                              const int* __restrict__ totals, const int* __restrict__ bbase,
                                              int* __restrict__ row_ptr, unsigned short* __restrict__ csr, int n) {
    __shared__ int hist[512], off[512];
    __shared__ unsigned short lcsr[DCAP];
    int t = threadIdx.x, b = blockIdx.x;
    int cnt = totals[b], base = bbase[b];
    hist[t] = 0;
    __syncthreads();
    for (int i = t; i < cnt; i += 512)
        atomicAdd(&hist[(pairs[base + i] >> 16) & 511], 1);
    __syncthreads();
    int v = hist[t];
    off[t] = v;
    __syncthreads();
    for (int o = 1; o < 512; o <<= 1) {
        int u = (t >= o) ? off[t - o] : 0;
        __syncthreads();
        off[t] += u;
        __syncthreads();
    }
    int excl = off[t] - v;
    int node = (b << BSH) + t;
    if (node < n) row_ptr[node] = base + excl;
    __syncthreads();
    hist[t] = excl;
    __syncthreads();
    for (int i = t; i < cnt; i += 512) {
        unsigned w = pairs[base + i];
        int r = atomicAdd(&hist[(w >> 16) & 511], 1);  // LDS only
        if (r < DCAP) lcsr[r] = (unsigned short)(w & 0xFFFFu);
    }
    __syncthreads();
    int lim = min(cnt, DCAP);
    for (int i = t; i < lim; i += 512) csr[base + i] = lcsr[i];
}

// ---------------- Column-sharded aggregation ----------------
// 8 groups = NSH column-shards (64 B each) x NSPLIT node-splits, mapped to XCDs
// via blockIdx%8 (round-robin dispatch heuristic: same group -> same XCD).
// Per-XCD working set = n*64B = 3.2 MB < 4 MiB L2 -> gather served from local L2.
// Each block first streams a chunk of its shard sequentially to fill L2 at
// streaming rates instead of random-line rates.
// Block = 256 threads = 64 nodes x 4 chunks (16 B each) of the 64 B slice.

#define ECAP3 2048

template <int TPN, int NSH, int NSPLIT, bool OUTF32>
__global__ __launch_bounds__(256) void agg_shard(
    const uint4* __restrict__ x, const int* __restrict__ row_ptr,
    const unsigned short* __restrict__ csr,
    uint4* __restrict__ outb,      // bf16 agg table (!OUTF32)
    float4* __restrict__ outf,     // f32 agg table (OUTF32)
    int n, int ngrp) {
    static_assert(NSH * NSPLIT == 8, "groups must equal XCD count");
    __shared__ unsigned short eidx[ECAP3];

    int t = threadIdx.x;
    int g = blockIdx.x & 7;
    int s = g % NSH, sp = g / NSH;
    int q = blockIdx.x >> 3;
    int ns = (n + NSPLIT - 1) / NSPLIT;
    int sbeg = sp * ns, send = min(sbeg + ns, n);
    int r0 = sbeg + q * 64;
    if (r0 >= send) return;
    int r1 = min(r0 + 64, send);

    // ---- L2 warm: stream this block's chunk of the shard (whole-table columns) ----
    {
        int W = (n * 4 + ngrp - 1) / ngrp;  // uint4 elements per block
        int w0 = q * W, w1 = min(w0 + W, n * 4);
        unsigned wacc = 0;
        for (int j = w0 + t; j < w1; j += 256) {
            uint4 wv = x[(size_t)(j >> 2) * TPN + s * 4 + (j & 3)];
            wacc ^= wv.x ^ wv.y ^ wv.z ^ wv.w;
        }
        asm volatile("" :: "v"(wacc));  // keep loads live (rule #17)
    }

    // ---- stage edge indices ----
    int E0 = row_ptr[r0];
    int E1 = row_ptr[r1];
    int ecnt = E1 - E0;
    bool fits = (ecnt <= ECAP3);
    int scnt = fits ? ecnt : ECAP3;
    for (int i = t; i < scnt; i += 256) eidx[i] = csr[E0 + i];
    __syncthreads();

    int node = r0 + (t >> 2), c = t & 3;
    int lane = s * 4 + c;
    if (node >= r1) return;

    float acc[8] = {0.f, 0.f, 0.f, 0.f, 0.f, 0.f, 0.f, 0.f};
    uint4 sv = x[(size_t)node * TPN + lane];
    ACC8(sv)
    int beg = row_ptr[node], end = row_ptr[node + 1];
    if (fits) {
        gather_acc<TPN>(acc, x, lane, beg - E0, end - E0,
                        [&](int k) { return (int)eidx[k]; });
    } else {
        gather_acc<TPN>(acc, x, lane, beg, end,
                        [&](int k) { return (int)csr[k]; });
    }

    if (OUTF32) {
        float4 o0 = make_float4(acc[0], acc[1], acc[2], acc[3]);
        float4 o1 = make_float4(acc[4], acc[5], acc[6], acc[7]);
        outf[((size_t)node * TPN + lane) * 2]     = o0;
        outf[((size_t)node * TPN + lane) * 2 + 1] = o1;
    } else {
        uint4 p;
        p.x = pack2(acc[0], acc[1]); p.y = pack2(acc[2], acc[3]);
        p.z = pack2(acc[4], acc[5]); p.w = pack2(acc[6], acc[7]);
        outb[(size_t)node * TPN + lane] = p;
    }
}

// ---------------- Dense GEMM on aggregated table (16-row strip per block) ----------------

template <bool SECOND>
__global__ __launch_bounds__(256) void gemm_dense(
    const uint4* __restrict__ A,          // bf16 [n x 128]
    const short8* __restrict__ Bt, const float* __restrict__ bias,
    unsigned short* __restrict__ out_h,   // !SECOND
    const short8* __restrict__ Bt2,       // SECOND
    unsigned short* __restrict__ out_y,   // SECOND
    int n) {
    __shared__ unsigned short As[16][136];
    __shared__ unsigned short Hs[SECOND ? 16 : 1][SECOND ? 136 : 1];

    int t = threadIdx.x;
    int r0 = blockIdx.x * 16;
    int lr = t >> 4, c = t & 15;
    uint4 av = make_uint4(0u, 0u, 0u, 0u);
    if (r0 + lr < n) av = A[(size_t)(r0 + lr) * 16 + c];
    ((uint4*)&As[lr][0])[c] = av;
    __syncthreads();

    int wid = t >> 6, lane = t & 63;
    int lm = lane & 15, lq = lane >> 4;

    short8 a[4];
#pragma unroll
    for (int kc = 0; kc < 4; kc++)
        a[kc] = *(const short8*)&As[lm][kc * 32 + lq * 8];

    f32x4 hacc[2];
#pragma unroll
    for (int nt = 0; nt < 2; nt++) hacc[nt] = (f32x4){0.f, 0.f, 0.f, 0.f};
#pragma unroll
    for (int nt = 0; nt < 2; nt++) {
        const short8* Br = Bt + (size_t)((wid * 2 + nt) * 16 + lm) * 16;
#pragma unroll
        for (int kc = 0; kc < 4; kc++)
            hacc[nt] = __builtin_amdgcn_mfma_f32_16x16x32_bf16(a[kc], Br[kc * 4 + lq], hacc[nt], 0, 0, 0);
    }

#pragma unroll
    for (int nt = 0; nt < 2; nt++) {
        int col = (wid * 2 + nt) * 16 + lm;
        float bv = bias[col];
#pragma unroll
        for (int i = 0; i < 4; i++) {
            int row = r0 + lq * 4 + i;
            float v = fmaxf(hacc[nt][i] + bv, 0.f);
            if (SECOND) {
                Hs[lq * 4 + i][col] = f2bf(v);
            } else if (row < n) {
                out_h[(size_t)row * 128 + col] = f2bf(v);
            }
        }
    }

    if (SECOND) {
        __syncthreads();
        short8 a2[4];
#pragma unroll
        for (int kc = 0; kc < 4; kc++)
            a2[kc] = *(const short8*)&Hs[lm][kc * 32 + lq * 8];
        f32x4 yacc = (f32x4){0.f, 0.f, 0.f, 0.f};
        const short8* Br2 = Bt2 + (size_t)(wid * 16 + lm) * 16;
#pragma unroll
        for (int kc = 0; kc < 4; kc++)
            yacc = __builtin_amdgcn_mfma_f32_16x16x32_bf16(a2[kc], Br2[kc * 4 + lq], yacc, 0, 0, 0);
        int col = wid * 16 + lm;
#pragma unroll
        for (int i = 0; i < 4; i++) {
            int row = r0 + lq * 4 + i;
            if (row < n) out_y[(size_t)row * 64 + col] = f2bf(yacc[i]);
        }
    }
}

// ---------------- log_softmax over fp32 agg table (D=64) ----------------
// Block = 256 threads = 32 rows x 8 chunks.

__global__ __launch_bounds__(256) void lsm_k(
    const float4* __restrict__ A3, float* __restrict__ out,
    const float* __restrict__ bo, int n) {
    int t = threadIdx.x;
    int node = blockIdx.x * 32 + (t >> 3), lane = t & 7;
    if (node >= n) return;

    float4 v0 = A3[(size_t)node * 16 + lane * 2];
    float4 v1 = A3[(size_t)node * 16 + lane * 2 + 1];
    float acc[8] = {v0.x, v0.y, v0.z, v0.w, v1.x, v1.y, v1.z, v1.w};

    const float4* bo4 = (const float4*)bo;
    float4 bA = bo4[lane * 2], bB = bo4[lane * 2 + 1];
    acc[0] += bA.x; acc[1] += bA.y; acc[2] += bA.z; acc[3] += bA.w;
    acc[4] += bB.x; acc[5] += bB.y; acc[6] += bB.z; acc[7] += bB.w;
    float m = acc[0];
#pragma unroll
    for (int j = 1; j < 8; j++) m = fmaxf(m, acc[j]);
#pragma unroll
    for (int off = 1; off < 8; off <<= 1) m = fmaxf(m, __shfl_xor(m, off, 64));
    float s = 0.f;
#pragma unroll
    for (int j = 0; j < 8; j++) s += __expf(acc[j] - m);
#pragma unroll
    for (int off = 1; off < 8; off <<= 1) s += __shfl_xor(s, off, 64);
    float ls = m + __logf(s);
    float4 o0 = make_float4(acc[0] - ls, acc[1] - ls, acc[2] - ls, acc[3] - ls);
    float4 o1 = make_float4(acc[4] - ls, acc[5] - ls, acc[6] - ls, acc[7] - ls);
    float4* op = (float4*)(out + (size_t)node * 64 + lane * 8);
    op[0] = o0;
    op[1] = o1;
}

// ---------------- launch ----------------

extern "C" void kernel_launch(void* const* d_in, const int* in_sizes, int n_in,
                              void* d_out, int out_size, void* d_ws, size_t ws_size,
                              hipStream_t stream) {
    const float* feature = (const float*)d_in[0];
    const int*   edges   = (const int*)d_in[1];
    const float* W1 = (const float*)d_in[2];
    const float* b1 = (const float*)d_in[3];
    const float* Wh = (const float*)d_in[4];
    const float* bh = (const float*)d_in[5];
    const float* Wo = (const float*)d_in[6];
    const float* bo = (const float*)d_in[7];

    int n = in_sizes[0] / 128;  // 50000 (< 65536 for 16-bit src packing)
    int e = in_sizes[1] / 2;    // 800000
    const int* src = edges;
    const int* dst = edges + e;

    int nbkt = (n + 511) >> BSH;
    int nblk = (e + EPB - 1) / EPB;
    int nf4 = n * 32;
    int cvtb = (nf4 + 255) / 256;

    char* ws = (char*)d_ws;
    auto take = [&](size_t bytes) {
        char* p = ws;
        ws += (bytes + 255) & ~(size_t)255;
        return p;
    };
    int* cnt2d   = (int*)take((size_t)nbkt * nblk * 4);
    int* totals  = (int*)take((size_t)nbkt * 4);
    int* bbase   = (int*)take((size_t)(nbkt + 1) * 4);
    int* row_ptr = (int*)take((size_t)(n + 1) * 4);
    unsigned* pairs = (unsigned*)take((size_t)e * 4);
    unsigned short* csr = (unsigned short*)take((size_t)e * 2);
    unsigned short* featb = (unsigned short*)take((size_t)n * 128 * 2);
    unsigned short* hb    = (unsigned short*)take((size_t)n * 128 * 2);
    unsigned short* yb    = (unsigned short*)take((size_t)n * 64 * 2);
    unsigned short* A1    = (unsigned short*)take((size_t)n * 128 * 2);  // agg partials (bf16), reused L1/L2
    unsigned short* W1t = (unsigned short*)take(128 * 128 * 2);
    unsigned short* Wht = (unsigned short*)take(128 * 128 * 2);
    unsigned short* Wot = (unsigned short*)take(64 * 128 * 2);
    // A3 (f32, n x 64 = 12.8 MB) overlays featb (12.8 MB): featb is dead after the
    // layer-1 aggregation; agg3 runs strictly later in the stream.
    float* A3f = (float*)featb;

    // CSR build + conversions (binA co-scheduled with cvt/wt)
    mega1<<<nblk + cvtb + 160, 256, 0, stream>>>(
        dst, cnt2d, e, nbkt, nblk,
        (const float4*)feature, (uint2*)featb, cvtb, nf4,
        W1, Wh, Wo, W1t, Wht, Wot);
    scanB1<<<nbkt, 512, 0, stream>>>(cnt2d, totals, nblk);
    scanB2<<<1, 128, 0, stream>>>(totals, bbase, row_ptr, nbkt, n, e);
    binC<<<nblk, 256, 0, stream>>>(src, dst, cnt2d, bbase, pairs, e, nbkt, nblk);
    buildD<<<nbkt, 512, 0, stream>>>(pairs, totals, bbase, row_ptr, csr, n);

    int gblocks = (n + 15) / 16;
    int ngrp1 = (((n + 1) / 2) + 63) / 64;   // node-halves of 25000 -> 391
    int ngrp3 = (((n + 3) / 4) + 63) / 64;   // node-quarters of 12500 -> 196

    // Layer 1: A1 = x + agg(x)  (4 col-shards x 2 halves);  h1 = relu(A1@W1+b1)
    agg_shard<16, 4, 2, false><<<8 * ngrp1, 256, 0, stream>>>(
        (const uint4*)featb, row_ptr, csr, (uint4*)A1, nullptr, n, ngrp1);
    gemm_dense<false><<<gblocks, 256, 0, stream>>>(
        (const uint4*)A1, (const short8*)W1t, b1, hb, nullptr, nullptr, n);

    // Layer 2: A2 = h1 + agg(h1);  h2 = relu(A2@Wh+bh);  y = h2@Wo
    agg_shard<16, 4, 2, false><<<8 * ngrp1, 256, 0, stream>>>(
        (const uint4*)hb, row_ptr, csr, (uint4*)A1, nullptr, n, ngrp1);
    gemm_dense<true><<<gblocks, 256, 0, stream>>>(
        (const uint4*)A1, (const short8*)Wht, bh, nullptr, (const short8*)Wot, yb, n);

    // Layer 3: A3 = y + agg(y) (f32, 2 col-shards x 4 quarters); out = lsm(A3 + bo)
    agg_shard<8, 2, 4, true><<<8 * ngrp3, 256, 0, stream>>>(
        (const uint4*)yb, row_ptr, csr, nullptr, (float4*)A3f, n, ngrp3);
    lsm_k<<<(n + 31) / 32, 256, 0, stream>>>(
        (const float4*)A3f, (float*)d_out, bo, n);
}

// Round 5
// 249.050 us; speedup vs baseline: 1.0511x; 1.0511x over previous
//
#include <hip/hip_runtime.h>

typedef short short8 __attribute__((ext_vector_type(8)));
typedef float f32x4 __attribute__((ext_vector_type(4)));
typedef unsigned u32x2 __attribute__((ext_vector_type(2)));
typedef unsigned u32x4 __attribute__((ext_vector_type(4)));

// ---------------- bf16 helpers ----------------

__device__ inline unsigned short f2bf(float f) {
    union { float f; unsigned u; } v; v.f = f;
    unsigned r = v.u + 0x7fffu + ((v.u >> 16) & 1u);
    return (unsigned short)(r >> 16);
}
__device__ inline unsigned pack2(float a, float b) {
    return (unsigned)f2bf(a) | ((unsigned)f2bf(b) << 16);
}
__device__ inline float bflo(unsigned u) { union { unsigned q; float f; } c; c.q = u << 16; return c.f; }
__device__ inline float bfhi(unsigned u) { union { unsigned q; float f; } c; c.q = u & 0xffff0000u; return c.f; }

#define ACC8(vv)                                     \
    acc[0] += bflo(vv.x); acc[1] += bfhi(vv.x);      \
    acc[2] += bflo(vv.y); acc[3] += bfhi(vv.y);      \
    acc[4] += bflo(vv.z); acc[5] += bfhi(vv.z);      \
    acc[6] += bflo(vv.w); acc[7] += bfhi(vv.w);

// Gather-accumulate over edges [beg,end); geti(k) supplies the row index.
// 16-wide batches; remainder via ONE masked 16-wide batch (indices clamped).
template <int TPN, typename F>
__device__ __forceinline__ void gather_acc(float acc[8], const uint4* __restrict__ x,
                                           int lane, int beg, int end, F geti) {
    int k = beg;
    for (; k + 16 <= end; k += 16) {
        int idx[16];
#pragma unroll
        for (int j = 0; j < 16; j++) idx[j] = geti(k + j);
        uint4 v[16];
#pragma unroll
        for (int j = 0; j < 16; j++) v[j] = x[(size_t)idx[j] * TPN + lane];
#pragma unroll
        for (int j = 0; j < 16; j++) { ACC8(v[j]) }
    }
    int r = end - k;
    if (r > 0) {
        int lim = end - 1;
        int idx[16];
#pragma unroll
        for (int j = 0; j < 16; j++) idx[j] = geti(min(k + j, lim));
        uint4 v[16];
#pragma unroll
        for (int j = 0; j < 16; j++) v[j] = x[(size_t)idx[j] * TPN + lane];
#pragma unroll
        for (int j = 0; j < 16; j++) {
            if (k + j < end) { ACC8(v[j]) }
        }
    }
}

// ---------------- CSR build: atomic-free two-level bucket sort ----------------

#define EPB 2048
#define NE 8
#define BSH 9
#define MAXBKT 128
#define DCAP 10240

// mega1: binA + feature->bf16 cvt (PANEL-major) + weight transposes
__global__ __launch_bounds__(256) void mega1(const int* __restrict__ dst, int* __restrict__ cnt2d,
                                             int e, int nbkt, int nblk,
                                             const float4* __restrict__ feat, unsigned* __restrict__ featb,
                                             int cvtb, int nf4,
                                             const float* __restrict__ W1, const float* __restrict__ Wh,
                                             const float* __restrict__ Wo,
                                             unsigned short* __restrict__ W1t, unsigned short* __restrict__ Wht,
                                             unsigned short* __restrict__ Wot) {
    __shared__ int hist[MAXBKT];
    int t = threadIdx.x, b = blockIdx.x;
    if (b < nblk) {
        for (int j = t; j < nbkt; j += 256) hist[j] = 0;
        __syncthreads();
        int base = b * EPB;
#pragma unroll
        for (int j = 0; j < NE; j++) {
            int idx = base + t + 256 * j;
            if (idx < e) atomicAdd(&hist[dst[idx] >> BSH], 1);
        }
        __syncthreads();
        for (int j = t; j < nbkt; j += 256) cnt2d[j * nblk + b] = hist[j];
    } else if (b < nblk + cvtb) {
        int i = (b - nblk) * 256 + t;
        if (i < nf4) {
            float4 v = feat[i];
            // panel-major: row = i>>5, j = i&31 (float4 within row), panel p = j>>3
            int row = i >> 5, j = i & 31;
            size_t n8 = (size_t)(nf4 >> 5) * 8;  // uint2 elems per panel
            u32x2 pk = {pack2(v.x, v.y), pack2(v.z, v.w)};
            u32x2* dstp = (u32x2*)featb + (size_t)(j >> 3) * n8 + (size_t)row * 8 + (j & 7);
            __builtin_nontemporal_store(pk, dstp);
        }
    } else {
        int i = (b - nblk - cvtb) * 256 + t;
        if (i < 16384) {
            int k = i >> 7, nn = i & 127;
            W1t[nn * 128 + k] = f2bf(W1[i]);
        } else if (i < 32768) {
            int j = i - 16384, k = j >> 7, nn = j & 127;
            Wht[nn * 128 + k] = f2bf(Wh[j]);
        } else if (i < 40960) {
            int j = i - 32768, k = j >> 6, nn = j & 63;
            Wot[nn * 128 + k] = f2bf(Wo[j]);
        }
    }
}

__global__ __launch_bounds__(512) void scanB1(int* __restrict__ cnt2d, int* __restrict__ totals, int nblk) {
    __shared__ int s[512];
    int t = threadIdx.x, b = blockIdx.x;
    int v = (t < nblk) ? cnt2d[b * nblk + t] : 0;
    s[t] = v;
    __syncthreads();
    for (int off = 1; off < 512; off <<= 1) {
        int u = (t >= off) ? s[t - off] : 0;
        __syncthreads();
        s[t] += u;
        __syncthreads();
    }
    if (t < nblk) cnt2d[b * nblk + t] = s[t] - v;
    if (t == nblk - 1) totals[b] = s[t];
}

__global__ __launch_bounds__(128) void scanB2(const int* __restrict__ totals, int* __restrict__ bbase,
                                              int* __restrict__ row_ptr, int nbkt, int n, int e) {
    __shared__ int s[128];
    int t = threadIdx.x;
    int v = (t < nbkt) ? totals[t] : 0;
    s[t] = v;
    __syncthreads();
    for (int off = 1; off < 128; off <<= 1) {
        int u = (t >= off) ? s[t - off] : 0;
        __syncthreads();
        s[t] += u;
        __syncthreads();
    }
    if (t < nbkt) bbase[t] = s[t] - v;
    if (t == 0) row_ptr[n] = e;
}

__global__ __launch_bounds__(256) void binC(const int* __restrict__ src, const int* __restrict__ dst,
                                            const int* __restrict__ cnt2d, const int* __restrict__ bbase,
                                            unsigned* __restrict__ pairs, int e, int nbkt, int nblk) {
    __shared__ int hist[MAXBKT], loff[MAXBKT], cur[MAXBKT], gb[MAXBKT];
    __shared__ int sc[256];
    __shared__ unsigned sorted[EPB];
    int t = threadIdx.x, blk = blockIdx.x;
    for (int b = t; b < nbkt; b += 256) hist[b] = 0;
    __syncthreads();
    int base = blk * EPB;
    int cnt = min(EPB, e - base);
    unsigned packed[NE];
    int bb[NE];
#pragma unroll
    for (int j = 0; j < NE; j++) {
        int idx = base + t + 256 * j;
        bb[j] = -1;
        if (idx < e) {
            unsigned s0 = (unsigned)src[idx], d = (unsigned)dst[idx];
            int b = (int)(d >> BSH);
            bb[j] = b;
            packed[j] = s0 | ((d & ((1u << BSH) - 1)) << 16) | ((unsigned)b << 25);
            atomicAdd(&hist[b], 1);
        }
    }
    __syncthreads();
    int v = (t < nbkt) ? hist[t] : 0;
    sc[t] = v;
    __syncthreads();
    for (int off = 1; off < 256; off <<= 1) {
        int u = (t >= off) ? sc[t - off] : 0;
        __syncthreads();
        sc[t] += u;
        __syncthreads();
    }
    if (t < nbkt) {
        int ex = sc[t] - v;
        loff[t] = ex;
        cur[t] = ex;
        gb[t] = bbase[t] + cnt2d[t * nblk + blk];
    }
    __syncthreads();
#pragma unroll
    for (int j = 0; j < NE; j++) {
        if (bb[j] >= 0) {
            int r = atomicAdd(&cur[bb[j]], 1);  // LDS only
            sorted[r] = packed[j];
        }
    }
    __syncthreads();
    for (int i = t; i < cnt; i += 256) {
        unsigned w = sorted[i];
        int b = (int)(w >> 25);
        pairs[gb[b] + (i - loff[b])] = w;
    }
}

__global__ __launch_bounds__(512) void buildD(const unsigned* __restrict__ pairs,
                                              const int* __restrict__ totals, const int* __restrict__ bbase,
                                              int* __restrict__ row_ptr, unsigned short* __restrict__ csr, int n) {
    __shared__ int hist[512], off[512];
    __shared__ unsigned short lcsr[DCAP];
    int t = threadIdx.x, b = blockIdx.x;
    int cnt = totals[b], base = bbase[b];
    hist[t] = 0;
    __syncthreads();
    for (int i = t; i < cnt; i += 512)
        atomicAdd(&hist[(pairs[base + i] >> 16) & 511], 1);
    __syncthreads();
    int v = hist[t];
    off[t] = v;
    __syncthreads();
    for (int o = 1; o < 512; o <<= 1) {
        int u = (t >= o) ? off[t - o] : 0;
        __syncthreads();
        off[t] += u;
        __syncthreads();
    }
    int excl = off[t] - v;
    int node = (b << BSH) + t;
    if (node < n) row_ptr[node] = base + excl;
    __syncthreads();
    hist[t] = excl;
    __syncthreads();
    for (int i = t; i < cnt; i += 512) {
        unsigned w = pairs[base + i];
        int r = atomicAdd(&hist[(w >> 16) & 511], 1);  // LDS only
        if (r < DCAP) lcsr[r] = (unsigned short)(w & 0xFFFFu);
    }
    __syncthreads();
    int lim = min(cnt, DCAP);
    for (int i = t; i < lim; i += 512) csr[base + i] = lcsr[i];
}

// ---------------- Column-sharded aggregation over CONTIGUOUS panels ----------------
// Layout: NSH panels, panel s = [n rows x 64 B] contiguous (3.2 MB) -> full L2
// index coverage, resident in one XCD's 4 MiB L2. Groups (s, split) pinned to XCDs
// via blockIdx&7 (round-robin dispatch). Outputs via non-temporal stores and edge
// staging via non-temporal loads so streams don't evict the panel.
// Block = 256 threads = 64 nodes x 4 chunks (16 B each).

#define ECAP3 2048

template <int NSH, int NSPLIT, bool OUTF32>
__global__ __launch_bounds__(256) void agg_shard(
    const uint4* __restrict__ xp,  // NSH contiguous panels, each n*4 uint4
    const int* __restrict__ row_ptr,
    const unsigned short* __restrict__ csr,
    unsigned* __restrict__ outb,   // bf16 panels, same layout (!OUTF32)
    float* __restrict__ outf,      // f32 [n x 64] (OUTF32)
    int n, int ngrp) {
    static_assert(NSH * NSPLIT == 8, "groups must equal XCD count");
    __shared__ unsigned short eidx[ECAP3];

    int t = threadIdx.x;
    int g = blockIdx.x & 7;
    int s = g % NSH, sp = g / NSH;
    int q = blockIdx.x >> 3;
    const uint4* x = xp + (size_t)s * n * 4;

    // ---- L2 warm: stream this block's chunk of the (contiguous) panel ----
    {
        int total = n * 4;
        int W = (total + ngrp - 1) / ngrp;
        int w0 = q * W, w1 = min(w0 + W, total);
        unsigned wacc = 0;
        for (int j = w0 + t; j < w1; j += 256) {
            uint4 wv = x[j];
            wacc ^= wv.x ^ wv.y ^ wv.z ^ wv.w;
        }
        asm volatile("" :: "v"(wacc));  // keep loads live
    }

    int ns = (n + NSPLIT - 1) / NSPLIT;
    int sbeg = sp * ns, send = min(sbeg + ns, n);
    int r0 = sbeg + q * 64;
    if (r0 >= send) return;
    int r1 = min(r0 + 64, send);

    // ---- stage edge indices (non-temporal: don't evict the panel) ----
    int E0 = row_ptr[r0];
    int E1 = row_ptr[r1];
    int ecnt = E1 - E0;
    bool fits = (ecnt <= ECAP3);
    int scnt = fits ? ecnt : ECAP3;
    for (int i = t; i < scnt; i += 256)
        eidx[i] = __builtin_nontemporal_load(&csr[E0 + i]);
    __syncthreads();

    int node = r0 + (t >> 2), c = t & 3;
    if (node >= r1) return;

    float acc[8] = {0.f, 0.f, 0.f, 0.f, 0.f, 0.f, 0.f, 0.f};
    uint4 sv = x[(size_t)node * 4 + c];
    ACC8(sv)
    int beg = row_ptr[node], end = row_ptr[node + 1];
    if (fits) {
        gather_acc<4>(acc, x, c, beg - E0, end - E0,
                      [&](int k) { return (int)eidx[k]; });
    } else {
        gather_acc<4>(acc, x, c, beg, end,
                      [&](int k) { return (int)csr[k]; });
    }

    if (OUTF32) {
        f32x4 o0 = {acc[0], acc[1], acc[2], acc[3]};
        f32x4 o1 = {acc[4], acc[5], acc[6], acc[7]};
        f32x4* op = (f32x4*)outf + (size_t)node * 16 + s * 8 + c * 2;
        __builtin_nontemporal_store(o0, op);
        __builtin_nontemporal_store(o1, op + 1);
    } else {
        u32x4 pk = {pack2(acc[0], acc[1]), pack2(acc[2], acc[3]),
                    pack2(acc[4], acc[5]), pack2(acc[6], acc[7])};
        u32x4* op = (u32x4*)outb + (size_t)s * n * 4 + (size_t)node * 4 + c;
        __builtin_nontemporal_store(pk, op);
    }
}

// ---------------- Dense GEMM on aggregated panels (16-row strip per block) ----------------
// A is 4 bf16 panels [n x 32 cols]; outputs written panel-major (nt stores).

template <bool SECOND>
__global__ __launch_bounds__(256) void gemm_dense(
    const uint4* __restrict__ A,          // 4 panels, each n*4 uint4
    const short8* __restrict__ Bt, const float* __restrict__ bias,
    unsigned short* __restrict__ out_h,   // !SECOND: 4 panels [n x 32]
    const short8* __restrict__ Bt2,       // SECOND
    unsigned short* __restrict__ out_y,   // SECOND: 2 panels [n x 32]
    int n) {
    __shared__ unsigned short As[16][136];
    __shared__ unsigned short Hs[SECOND ? 16 : 1][SECOND ? 136 : 1];

    int t = threadIdx.x;
    int r0 = blockIdx.x * 16;
    int lr = t >> 4, c = t & 15;
    uint4 av = make_uint4(0u, 0u, 0u, 0u);
    if (r0 + lr < n)
        av = A[(size_t)(c >> 2) * n * 4 + (size_t)(r0 + lr) * 4 + (c & 3)];
    ((uint4*)&As[lr][0])[c] = av;
    __syncthreads();

    int wid = t >> 6, lane = t & 63;
    int lm = lane & 15, lq = lane >> 4;

    short8 a[4];
#pragma unroll
    for (int kc = 0; kc < 4; kc++)
        a[kc] = *(const short8*)&As[lm][kc * 32 + lq * 8];

    f32x4 hacc[2];
#pragma unroll
    for (int nt = 0; nt < 2; nt++) hacc[nt] = (f32x4){0.f, 0.f, 0.f, 0.f};
#pragma unroll
    for (int nt = 0; nt < 2; nt++) {
        const short8* Br = Bt + (size_t)((wid * 2 + nt) * 16 + lm) * 16;
#pragma unroll
        for (int kc = 0; kc < 4; kc++)
            hacc[nt] = __builtin_amdgcn_mfma_f32_16x16x32_bf16(a[kc], Br[kc * 4 + lq], hacc[nt], 0, 0, 0);
    }

#pragma unroll
    for (int nt = 0; nt < 2; nt++) {
        int col = (wid * 2 + nt) * 16 + lm;
        float bv = bias[col];
#pragma unroll
        for (int i = 0; i < 4; i++) {
            int row = r0 + lq * 4 + i;
            float v = fmaxf(hacc[nt][i] + bv, 0.f);
            if (SECOND) {
                Hs[lq * 4 + i][col] = f2bf(v);
            } else if (row < n) {
                unsigned short hv = f2bf(v);
                __builtin_nontemporal_store(
                    hv, &out_h[(size_t)(col >> 5) * n * 32 + (size_t)row * 32 + (col & 31)]);
            }
        }
    }

    if (SECOND) {
        __syncthreads();
        short8 a2[4];
#pragma unroll
        for (int kc = 0; kc < 4; kc++)
            a2[kc] = *(const short8*)&Hs[lm][kc * 32 + lq * 8];
        f32x4 yacc = (f32x4){0.f, 0.f, 0.f, 0.f};
        const short8* Br2 = Bt2 + (size_t)(wid * 16 + lm) * 16;
#pragma unroll
        for (int kc = 0; kc < 4; kc++)
            yacc = __builtin_amdgcn_mfma_f32_16x16x32_bf16(a2[kc], Br2[kc * 4 + lq], yacc, 0, 0, 0);
        int col = wid * 16 + lm;
#pragma unroll
        for (int i = 0; i < 4; i++) {
            int row = r0 + lq * 4 + i;
            if (row < n) {
                unsigned short yv = f2bf(yacc[i]);
                __builtin_nontemporal_store(
                    yv, &out_y[(size_t)(col >> 5) * n * 32 + (size_t)row * 32 + (col & 31)]);
            }
        }
    }
}

// ---------------- log_softmax over fp32 agg table (D=64) ----------------
// Block = 256 threads = 32 rows x 8 chunks.

__global__ __launch_bounds__(256) void lsm_k(
    const float4* __restrict__ A3, float* __restrict__ out,
    const float* __restrict__ bo, int n) {
    int t = threadIdx.x;
    int node = blockIdx.x * 32 + (t >> 3), lane = t & 7;
    if (node >= n) return;

    float4 v0 = A3[(size_t)node * 16 + lane * 2];
    float4 v1 = A3[(size_t)node * 16 + lane * 2 + 1];
    float acc[8] = {v0.x, v0.y, v0.z, v0.w, v1.x, v1.y, v1.z, v1.w};

    const float4* bo4 = (const float4*)bo;
    float4 bA = bo4[lane * 2], bB = bo4[lane * 2 + 1];
    acc[0] += bA.x; acc[1] += bA.y; acc[2] += bA.z; acc[3] += bA.w;
    acc[4] += bB.x; acc[5] += bB.y; acc[6] += bB.z; acc[7] += bB.w;
    float m = acc[0];
#pragma unroll
    for (int j = 1; j < 8; j++) m = fmaxf(m, acc[j]);
#pragma unroll
    for (int off = 1; off < 8; off <<= 1) m = fmaxf(m, __shfl_xor(m, off, 64));
    float s = 0.f;
#pragma unroll
    for (int j = 0; j < 8; j++) s += __expf(acc[j] - m);
#pragma unroll
    for (int off = 1; off < 8; off <<= 1) s += __shfl_xor(s, off, 64);
    float ls = m + __logf(s);
    float4 o0 = make_float4(acc[0] - ls, acc[1] - ls, acc[2] - ls, acc[3] - ls);
    float4 o1 = make_float4(acc[4] - ls, acc[5] - ls, acc[6] - ls, acc[7] - ls);
    float4* op = (float4*)(out + (size_t)node * 64 + lane * 8);
    op[0] = o0;
    op[1] = o1;
}

// ---------------- launch ----------------

extern "C" void kernel_launch(void* const* d_in, const int* in_sizes, int n_in,
                              void* d_out, int out_size, void* d_ws, size_t ws_size,
                              hipStream_t stream) {
    const float* feature = (const float*)d_in[0];
    const int*   edges   = (const int*)d_in[1];
    const float* W1 = (const float*)d_in[2];
    const float* b1 = (const float*)d_in[3];
    const float* Wh = (const float*)d_in[4];
    const float* bh = (const float*)d_in[5];
    const float* Wo = (const float*)d_in[6];
    const float* bo = (const float*)d_in[7];

    int n = in_sizes[0] / 128;  // 50000 (< 65536 for 16-bit src packing)
    int e = in_sizes[1] / 2;    // 800000
    const int* src = edges;
    const int* dst = edges + e;

    int nbkt = (n + 511) >> BSH;
    int nblk = (e + EPB - 1) / EPB;
    int nf4 = n * 32;
    int cvtb = (nf4 + 255) / 256;

    char* ws = (char*)d_ws;
    auto take = [&](size_t bytes) {
        char* p = ws;
        ws += (bytes + 255) & ~(size_t)255;
        return p;
    };
    int* cnt2d   = (int*)take((size_t)nbkt * nblk * 4);
    int* totals  = (int*)take((size_t)nbkt * 4);
    int* bbase   = (int*)take((size_t)(nbkt + 1) * 4);
    int* row_ptr = (int*)take((size_t)(n + 1) * 4);
    unsigned* pairs = (unsigned*)take((size_t)e * 4);
    unsigned short* csr = (unsigned short*)take((size_t)e * 2);
    unsigned short* featb = (unsigned short*)take((size_t)n * 128 * 2);  // 4 panels
    unsigned short* hb    = (unsigned short*)take((size_t)n * 128 * 2);  // 4 panels
    unsigned short* yb    = (unsigned short*)take((size_t)n * 64 * 2);   // 2 panels
    unsigned short* A1    = (unsigned short*)take((size_t)n * 128 * 2);  // 4 panels
    unsigned short* W1t = (unsigned short*)take(128 * 128 * 2);
    unsigned short* Wht = (unsigned short*)take(128 * 128 * 2);
    unsigned short* Wot = (unsigned short*)take(64 * 128 * 2);
    // A3 (f32, n x 64 = 12.8 MB) overlays featb (12.8 MB): featb dead after agg1.
    float* A3f = (float*)featb;

    // CSR build + conversions
    mega1<<<nblk + cvtb + 160, 256, 0, stream>>>(
        dst, cnt2d, e, nbkt, nblk,
        (const float4*)feature, (unsigned*)featb, cvtb, nf4,
        W1, Wh, Wo, W1t, Wht, Wot);
    scanB1<<<nbkt, 512, 0, stream>>>(cnt2d, totals, nblk);
    scanB2<<<1, 128, 0, stream>>>(totals, bbase, row_ptr, nbkt, n, e);
    binC<<<nblk, 256, 0, stream>>>(src, dst, cnt2d, bbase, pairs, e, nbkt, nblk);
    buildD<<<nbkt, 512, 0, stream>>>(pairs, totals, bbase, row_ptr, csr, n);

    int gblocks = (n + 15) / 16;
    int ngrp1 = (((n + 1) / 2) + 63) / 64;   // node-halves -> 391
    int ngrp3 = (((n + 3) / 4) + 63) / 64;   // node-quarters -> 196

    // Layer 1: A1 = x + agg(x)  (4 panels x 2 halves);  h1 = relu(A1@W1+b1)
    agg_shard<4, 2, false><<<8 * ngrp1, 256, 0, stream>>>(
        (const uint4*)featb, row_ptr, csr, (unsigned*)A1, nullptr, n, ngrp1);
    gemm_dense<false><<<gblocks, 256, 0, stream>>>(
        (const uint4*)A1, (const short8*)W1t, b1, hb, nullptr, nullptr, n);

    // Layer 2: A2 = h1 + agg(h1);  h2 = relu(A2@Wh+bh);  y = h2@Wo
    agg_shard<4, 2, false><<<8 * ngrp1, 256, 0, stream>>>(
        (const uint4*)hb, row_ptr, csr, (unsigned*)A1, nullptr, n, ngrp1);
    gemm_dense<true><<<gblocks, 256, 0, stream>>>(
        (const uint4*)A1, (const short8*)Wht, bh, nullptr, (const short8*)Wot, yb, n);

    // Layer 3: A3 = y + agg(y) (f32, 2 panels x 4 quarters); out = lsm(A3 + bo)
    agg_shard<2, 4, true><<<8 * ngrp3, 256, 0, stream>>>(
        (const uint4*)yb, row_ptr, csr, nullptr, A3f, n, ngrp3);
    lsm_k<<<(n + 31) / 32, 256, 0, stream>>>(
        (const float4*)A3f, (float*)d_out, bo, n);
}

// Round 6
// 210.559 us; speedup vs baseline: 1.2432x; 1.1828x over previous
//
#include <hip/hip_runtime.h>

typedef short short8 __attribute__((ext_vector_type(8)));
typedef float f32x4 __attribute__((ext_vector_type(4)));

// ---------------- bf16 helpers ----------------

__device__ inline unsigned short f2bf(float f) {
    union { float f; unsigned u; } v; v.f = f;
    unsigned r = v.u + 0x7fffu + ((v.u >> 16) & 1u);
    return (unsigned short)(r >> 16);
}
__device__ inline unsigned pack2(float a, float b) {
    return (unsigned)f2bf(a) | ((unsigned)f2bf(b) << 16);
}
__device__ inline float bflo(unsigned u) { union { unsigned q; float f; } c; c.q = u << 16; return c.f; }
__device__ inline float bfhi(unsigned u) { union { unsigned q; float f; } c; c.q = u & 0xffff0000u; return c.f; }

#define ACC8(vv)                                     \
    acc[0] += bflo(vv.x); acc[1] += bfhi(vv.x);      \
    acc[2] += bflo(vv.y); acc[3] += bfhi(vv.y);      \
    acc[4] += bflo(vv.z); acc[5] += bfhi(vv.z);      \
    acc[6] += bflo(vv.w); acc[7] += bfhi(vv.w);

// Gather-accumulate over edges [beg,end); geti(k) supplies the row index
// (LDS-staged on the fast path). 16-wide batches keep 16 row loads in flight;
// the remainder is handled by ONE masked 16-wide batch (indices clamped to the
// last real edge -> duplicate loads coalesce onto already-fetched lines).
template <int TPN, typename F>
__device__ __forceinline__ void gather_acc(float acc[8], const uint4* __restrict__ x,
                                           int lane, int beg, int end, F geti) {
    int k = beg;
    for (; k + 16 <= end; k += 16) {
        int idx[16];
#pragma unroll
        for (int j = 0; j < 16; j++) idx[j] = geti(k + j);
        uint4 v[16];
#pragma unroll
        for (int j = 0; j < 16; j++) v[j] = x[(size_t)idx[j] * TPN + lane];
#pragma unroll
        for (int j = 0; j < 16; j++) { ACC8(v[j]) }
    }
    int r = end - k;
    if (r > 0) {
        int lim = end - 1;
        int idx[16];
#pragma unroll
        for (int j = 0; j < 16; j++) idx[j] = geti(min(k + j, lim));
        uint4 v[16];
#pragma unroll
        for (int j = 0; j < 16; j++) v[j] = x[(size_t)idx[j] * TPN + lane];
#pragma unroll
        for (int j = 0; j < 16; j++) {
            if (k + j < end) { ACC8(v[j]) }
        }
    }
}

// ---------------- CSR build: atomic-free two-level bucket sort ----------------

#define EPB 2048
#define NE 8
#define BSH 9
#define MAXBKT 128
#define DCAP 10240

// mega1: binA (blocks [0,nblk)) + feature->bf16 cvt + weight transposes, one launch
__global__ __launch_bounds__(256) void mega1(const int* __restrict__ dst, int* __restrict__ cnt2d,
                                             int e, int nbkt, int nblk,
                                             const float4* __restrict__ feat, uint2* __restrict__ featb,
                                             int cvtb, int nf4,
                                             const float* __restrict__ W1, const float* __restrict__ Wh,
                                             const float* __restrict__ Wo,
                                             unsigned short* __restrict__ W1t, unsigned short* __restrict__ Wht,
                                             unsigned short* __restrict__ Wot,
                                             int* __restrict__ ctr) {
    __shared__ int hist[MAXBKT];
    int t = threadIdx.x, b = blockIdx.x;
    if (b == 0 && t == 0) *ctr = 0;  // re-zero every replay (workspace is poisoned)
    if (b < nblk) {
        for (int j = t; j < nbkt; j += 256) hist[j] = 0;
        __syncthreads();
        int base = b * EPB;
#pragma unroll
        for (int j = 0; j < NE; j++) {
            int idx = base + t + 256 * j;
            if (idx < e) atomicAdd(&hist[dst[idx] >> BSH], 1);
        }
        __syncthreads();
        for (int j = t; j < nbkt; j += 256) cnt2d[j * nblk + b] = hist[j];
    } else if (b < nblk + cvtb) {
        int i = (b - nblk) * 256 + t;
        if (i < nf4) {
            float4 v = feat[i];
            featb[i] = make_uint2(pack2(v.x, v.y), pack2(v.z, v.w));
        }
    } else {
        int i = (b - nblk - cvtb) * 256 + t;
        if (i < 16384) {
            int k = i >> 7, nn = i & 127;
            W1t[nn * 128 + k] = f2bf(W1[i]);
        } else if (i < 32768) {
            int j = i - 16384, k = j >> 7, nn = j & 127;
            Wht[nn * 128 + k] = f2bf(Wh[j]);
        } else if (i < 40960) {
            int j = i - 32768, k = j >> 6, nn = j & 63;
            Wot[nn * 128 + k] = f2bf(Wo[j]);
        }
    }
}

// scanB: per-bucket scan over block counts; LAST block also computes the bucket
// bases (old scanB2) via device-scope counter handshake -> one launch saved.
__global__ __launch_bounds__(512) void scanB(int* __restrict__ cnt2d, int* __restrict__ totals,
                                             int* __restrict__ bbase, int* __restrict__ row_ptr,
                                             int* __restrict__ ctr, int nblk, int nbkt, int n, int e) {
    __shared__ int s[512];
    __shared__ int lastFlag;
    int t = threadIdx.x, b = blockIdx.x;
    int v = (t < nblk) ? cnt2d[b * nblk + t] : 0;
    s[t] = v;
    __syncthreads();
    for (int off = 1; off < 512; off <<= 1) {
        int u = (t >= off) ? s[t - off] : 0;
        __syncthreads();
        s[t] += u;
        __syncthreads();
    }
    if (t < nblk) cnt2d[b * nblk + t] = s[t] - v;
    if (t == nblk - 1) {
        totals[b] = s[t];
        __threadfence();  // release: totals visible before the signal
    }
    __syncthreads();
    if (t == 0) {
        int old = atomicAdd(ctr, 1);  // device-scope
        lastFlag = (old == gridDim.x - 1);
        if (lastFlag) __threadfence();  // acquire: see all totals
    }
    __syncthreads();
    if (lastFlag) {
        int v2 = (t < nbkt) ? totals[t] : 0;
        s[t] = v2;
        __syncthreads();
        for (int off = 1; off < 512; off <<= 1) {
            int u = (t >= off) ? s[t - off] : 0;
            __syncthreads();
            s[t] += u;
            __syncthreads();
        }
        if (t < nbkt) bbase[t] = s[t] - v2;
        if (t == 0) row_ptr[n] = e;
    }
}

__global__ __launch_bounds__(256) void binC(const int* __restrict__ src, const int* __restrict__ dst,
                                            const int* __restrict__ cnt2d, const int* __restrict__ bbase,
                                            unsigned* __restrict__ pairs, int e, int nbkt, int nblk) {
    __shared__ int hist[MAXBKT], loff[MAXBKT], cur[MAXBKT], gb[MAXBKT];
    __shared__ int sc[256];
    __shared__ unsigned sorted[EPB];
    int t = threadIdx.x, blk = blockIdx.x;
    for (int b = t; b < nbkt; b += 256) hist[b] = 0;
    __syncthreads();
    int base = blk * EPB;
    int cnt = min(EPB, e - base);
    unsigned packed[NE];
    int bb[NE];
#pragma unroll
    for (int j = 0; j < NE; j++) {
        int idx = base + t + 256 * j;
        bb[j] = -1;
        if (idx < e) {
            unsigned s0 = (unsigned)src[idx], d = (unsigned)dst[idx];
            int b = (int)(d >> BSH);
            bb[j] = b;
            packed[j] = s0 | ((d & ((1u << BSH) - 1)) << 16) | ((unsigned)b << 25);
            atomicAdd(&hist[b], 1);
        }
    }
    __syncthreads();
    int v = (t < nbkt) ? hist[t] : 0;
    sc[t] = v;
    __syncthreads();
    for (int off = 1; off < 256; off <<= 1) {
        int u = (t >= off) ? sc[t - off] : 0;
        __syncthreads();
        sc[t] += u;
        __syncthreads();
    }
    if (t < nbkt) {
        int ex = sc[t] - v;
        loff[t] = ex;
        cur[t] = ex;
        gb[t] = bbase[t] + cnt2d[t * nblk + blk];
    }
    __syncthreads();
#pragma unroll
    for (int j = 0; j < NE; j++) {
        if (bb[j] >= 0) {
            int r = atomicAdd(&cur[bb[j]], 1);  // LDS only
            sorted[r] = packed[j];
        }
    }
    __syncthreads();
    for (int i = t; i < cnt; i += 256) {
        unsigned w = sorted[i];
        int b = (int)(w >> 25);
        pairs[gb[b] + (i - loff[b])] = w;
    }
}

__global__ __launch_bounds__(512) void buildD(const unsigned* __restrict__ pairs,
                                              const int* __restrict__ totals, const int* __restrict__ bbase,
                                              int* __restrict__ row_ptr, unsigned short* __restrict__ csr, int n) {
    __shared__ int hist[512], off[512];
    __shared__ unsigned short lcsr[DCAP];
    int t = threadIdx.x, b = blockIdx.x;
    int cnt = totals[b], base = bbase[b];
    hist[t] = 0;
    __syncthreads();
    for (int i = t; i < cnt; i += 512)
        atomicAdd(&hist[(pairs[base + i] >> 16) & 511], 1);
    __syncthreads();
    int v = hist[t];
    off[t] = v;
    __syncthreads();
    for (int o = 1; o < 512; o <<= 1) {
        int u = (t >= o) ? off[t - o] : 0;
        __syncthreads();
        off[t] += u;
        __syncthreads();
    }
    int excl = off[t] - v;
    int node = (b << BSH) + t;
    if (node < n) row_ptr[node] = base + excl;
    __syncthreads();
    hist[t] = excl;
    __syncthreads();
    for (int i = t; i < cnt; i += 512) {
        unsigned w = pairs[base + i];
        int r = atomicAdd(&hist[(w >> 16) & 511], 1);  // LDS only
        if (r < DCAP) lcsr[r] = (unsigned short)(w & 0xFFFFu);
    }
    __syncthreads();
    int lim = min(cnt, DCAP);
    for (int i = t; i < lim; i += 512) csr[base + i] = lcsr[i];
}

// ---------------- Fused layer (node-parallel gather + MFMA GEMM) ----------------
// Block = 256 threads = 16 nodes x 16 chunks. Tile rows exactly match one MFMA 16-row strip.

#define ECAP 1024   // block edge-index LDS cap; mean 256, >40 sigma headroom

template <bool SECOND>
__global__ __launch_bounds__(256) void fused_layer(
    const uint4* __restrict__ x, const int* __restrict__ row_ptr,
    const unsigned short* __restrict__ csr,
    const short8* __restrict__ Bt, const float* __restrict__ bias,
    unsigned short* __restrict__ out_h,   // !SECOND
    const short8* __restrict__ Bt2,       // SECOND
    unsigned short* __restrict__ out_y,   // SECOND
    int n) {
    __shared__ unsigned short As[16][136];  // +8 halves pad
    __shared__ unsigned short Hs[SECOND ? 16 : 1][SECOND ? 136 : 1];
    __shared__ unsigned short eidx[ECAP];

    int t = threadIdx.x;
    int nl = t >> 4, chunk = t & 15;
    int r0 = blockIdx.x * 16;
    int node = r0 + nl;

    // hoist independent global loads above the staging barrier (hide one round)
    int beg = 0, end = 0;
    uint4 s0 = make_uint4(0u, 0u, 0u, 0u);
    if (node < n) {
        beg = row_ptr[node];
        end = row_ptr[node + 1];
        s0 = x[(size_t)node * 16 + chunk];
    }

    // stage this block's (contiguous) edge indices into LDS
    int E0 = row_ptr[r0];
    int E1 = row_ptr[min(r0 + 16, n)];
    int ecnt = min(E1 - E0, ECAP);
    for (int i = t; i < ecnt; i += 256) eidx[i] = csr[E0 + i];
    __syncthreads();

    // ---- Phase 1: aggregation into registers ----
    float acc[8] = {0.f, 0.f, 0.f, 0.f, 0.f, 0.f, 0.f, 0.f};
    if (node < n) {
        ACC8(s0)
        if (end - E0 <= ECAP) {
            gather_acc<16>(acc, x, chunk, beg - E0, end - E0,
                           [&](int k) { return (int)eidx[k]; });
        } else {
            gather_acc<16>(acc, x, chunk, beg, end,
                           [&](int k) { return (int)csr[k]; });
        }
    }
    uint4 packed;
    packed.x = pack2(acc[0], acc[1]); packed.y = pack2(acc[2], acc[3]);
    packed.z = pack2(acc[4], acc[5]); packed.w = pack2(acc[6], acc[7]);
    ((uint4*)&As[nl][0])[chunk] = packed;
    __syncthreads();

    // ---- Phase 2: GEMM 16x128 @ 128x128 ----
    int wid = t >> 6, lane = t & 63;
    int lm = lane & 15, lq = lane >> 4;

    short8 a[4];
#pragma unroll
    for (int kc = 0; kc < 4; kc++)
        a[kc] = *(const short8*)&As[lm][kc * 32 + lq * 8];

    f32x4 hacc[2];
#pragma unroll
    for (int nt = 0; nt < 2; nt++) hacc[nt] = (f32x4){0.f, 0.f, 0.f, 0.f};
#pragma unroll
    for (int nt = 0; nt < 2; nt++) {
        const short8* Br = Bt + (size_t)((wid * 2 + nt) * 16 + lm) * 16;
#pragma unroll
        for (int kc = 0; kc < 4; kc++)
            hacc[nt] = __builtin_amdgcn_mfma_f32_16x16x32_bf16(a[kc], Br[kc * 4 + lq], hacc[nt], 0, 0, 0);
    }

    // ---- Epilogue ----
#pragma unroll
    for (int nt = 0; nt < 2; nt++) {
        int col = (wid * 2 + nt) * 16 + lm;
        float bv = bias[col];
#pragma unroll
        for (int i = 0; i < 4; i++) {
            int row = r0 + lq * 4 + i;
            float v = fmaxf(hacc[nt][i] + bv, 0.f);
            if (SECOND) {
                Hs[lq * 4 + i][col] = f2bf(v);
            } else if (row < n) {
                out_h[(size_t)row * 128 + col] = f2bf(v);
            }
        }
    }

    if (SECOND) {
        __syncthreads();
        short8 a2[4];
#pragma unroll
        for (int kc = 0; kc < 4; kc++)
            a2[kc] = *(const short8*)&Hs[lm][kc * 32 + lq * 8];
        f32x4 yacc = (f32x4){0.f, 0.f, 0.f, 0.f};
        const short8* Br2 = Bt2 + (size_t)(wid * 16 + lm) * 16;
#pragma unroll
        for (int kc = 0; kc < 4; kc++)
            yacc = __builtin_amdgcn_mfma_f32_16x16x32_bf16(a2[kc], Br2[kc * 4 + lq], yacc, 0, 0, 0);
        int col = wid * 16 + lm;
#pragma unroll
        for (int i = 0; i < 4; i++) {
            int row = r0 + lq * 4 + i;
            if (row < n) out_y[(size_t)row * 64 + col] = f2bf(yacc[i]);
        }
    }
}

// ---------------- Final aggregation (D=64) + bo + log_softmax ----------------
// Block = 256 threads = 32 nodes x 8 chunks.

#define ECAP2 1536  // mean 512, >40 sigma headroom

__global__ __launch_bounds__(256) void agg_lsm(
    const uint4* __restrict__ x, float* __restrict__ out,
    const int* __restrict__ row_ptr, const unsigned short* __restrict__ csr,
    const float* __restrict__ bo, int n) {
    __shared__ unsigned short eidx[ECAP2];
    int t = threadIdx.x;
    int r0 = blockIdx.x * 32;
    int node = r0 + (t >> 3), lane = t & 7;

    // hoist independent global loads above the staging barrier
    int beg = 0, end = 0;
    uint4 s0 = make_uint4(0u, 0u, 0u, 0u);
    if (node < n) {
        beg = row_ptr[node];
        end = row_ptr[node + 1];
        s0 = x[(size_t)node * 8 + lane];
    }

    int E0 = row_ptr[r0];
    int E1 = row_ptr[min(r0 + 32, n)];
    int ecnt = min(E1 - E0, ECAP2);
    for (int i = t; i < ecnt; i += 256) eidx[i] = csr[E0 + i];
    __syncthreads();

    if (node >= n) return;
    float acc[8] = { bflo(s0.x), bfhi(s0.x), bflo(s0.y), bfhi(s0.y),
                     bflo(s0.z), bfhi(s0.z), bflo(s0.w), bfhi(s0.w) };
    if (end - E0 <= ECAP2) {
        gather_acc<8>(acc, x, lane, beg - E0, end - E0,
                      [&](int k) { return (int)eidx[k]; });
    } else {
        gather_acc<8>(acc, x, lane, beg, end,
                      [&](int k) { return (int)csr[k]; });
    }

    const float4* bo4 = (const float4*)bo;
    float4 bA = bo4[lane * 2], bB = bo4[lane * 2 + 1];
    acc[0] += bA.x; acc[1] += bA.y; acc[2] += bA.z; acc[3] += bA.w;
    acc[4] += bB.x; acc[5] += bB.y; acc[6] += bB.z; acc[7] += bB.w;
    float m = acc[0];
#pragma unroll
    for (int j = 1; j < 8; j++) m = fmaxf(m, acc[j]);
#pragma unroll
    for (int off = 1; off < 8; off <<= 1) m = fmaxf(m, __shfl_xor(m, off, 64));
    float s = 0.f;
#pragma unroll
    for (int j = 0; j < 8; j++) s += __expf(acc[j] - m);
#pragma unroll
    for (int off = 1; off < 8; off <<= 1) s += __shfl_xor(s, off, 64);
    float ls = m + __logf(s);
    float4 o0 = make_float4(acc[0] - ls, acc[1] - ls, acc[2] - ls, acc[3] - ls);
    float4 o1 = make_float4(acc[4] - ls, acc[5] - ls, acc[6] - ls, acc[7] - ls);
    float4* op = (float4*)(out + (size_t)node * 64 + lane * 8);
    op[0] = o0;
    op[1] = o1;
}

// ---------------- launch ----------------

extern "C" void kernel_launch(void* const* d_in, const int* in_sizes, int n_in,
                              void* d_out, int out_size, void* d_ws, size_t ws_size,
                              hipStream_t stream) {
    const float* feature = (const float*)d_in[0];
    const int*   edges   = (const int*)d_in[1];
    const float* W1 = (const float*)d_in[2];
    const float* b1 = (const float*)d_in[3];
    const float* Wh = (const float*)d_in[4];
    const float* bh = (const float*)d_in[5];
    const float* Wo = (const float*)d_in[6];
    const float* bo = (const float*)d_in[7];

    int n = in_sizes[0] / 128;  // 50000 (< 65536 for 16-bit src packing)
    int e = in_sizes[1] / 2;    // 800000
    const int* src = edges;
    const int* dst = edges + e;

    int nbkt = (n + 511) >> BSH;
    int nblk = (e + EPB - 1) / EPB;
    int nf4 = n * 32;
    int cvtb = (nf4 + 255) / 256;

    char* ws = (char*)d_ws;
    auto take = [&](size_t bytes) {
        char* p = ws;
        ws += (bytes + 255) & ~(size_t)255;
        return p;
    };
    int* cnt2d   = (int*)take((size_t)nbkt * nblk * 4);
    int* totals  = (int*)take((size_t)nbkt * 4);
    int* bbase   = (int*)take((size_t)(nbkt + 1) * 4);
    int* row_ptr = (int*)take((size_t)(n + 1) * 4);
    int* ctr     = (int*)take(4);
    unsigned* pairs = (unsigned*)take((size_t)e * 4);
    unsigned short* csr = (unsigned short*)take((size_t)e * 2);
    unsigned short* featb = (unsigned short*)take((size_t)n * 128 * 2);
    unsigned short* hb    = (unsigned short*)take((size_t)n * 128 * 2);
    unsigned short* yb    = (unsigned short*)take((size_t)n * 64 * 2);
    unsigned short* W1t = (unsigned short*)take(128 * 128 * 2);
    unsigned short* Wht = (unsigned short*)take(128 * 128 * 2);
    unsigned short* Wot = (unsigned short*)take(64 * 128 * 2);

    // CSR build + conversions (binA co-scheduled with cvt/wt)
    mega1<<<nblk + cvtb + 160, 256, 0, stream>>>(
        dst, cnt2d, e, nbkt, nblk,
        (const float4*)feature, (uint2*)featb, cvtb, nf4,
        W1, Wh, Wo, W1t, Wht, Wot, ctr);
    scanB<<<nbkt, 512, 0, stream>>>(cnt2d, totals, bbase, row_ptr, ctr, nblk, nbkt, n, e);
    binC<<<nblk, 256, 0, stream>>>(src, dst, cnt2d, bbase, pairs, e, nbkt, nblk);
    buildD<<<nbkt, 512, 0, stream>>>(pairs, totals, bbase, row_ptr, csr, n);

    int fblocks = (n + 15) / 16;

    // Layer 1: h1 = relu((x+agg(x))@W1+b1)
    fused_layer<false><<<fblocks, 256, 0, stream>>>(
        (const uint4*)featb, row_ptr, csr, (const short8*)W1t, b1,
        hb, nullptr, nullptr, n);

    // Layer 2 + layer-3 GEMM: h2 = relu((h1+agg(h1))@Wh+bh); y = h2@Wo
    fused_layer<true><<<fblocks, 256, 0, stream>>>(
        (const uint4*)hb, row_ptr, csr, (const short8*)Wht, bh,
        nullptr, (const short8*)Wot, yb, n);

    // out = log_softmax(y + agg(y) + bo)
    agg_lsm<<<(n + 31) / 32, 256, 0, stream>>>(
        (const uint4*)yb, (float*)d_out, row_ptr, csr, bo, n);
}